// Round 2
// baseline (451.660 us; speedup 1.0000x reference)
//
#include <hip/hip_runtime.h>
#include <hip/hip_bf16.h>
#include <math.h>

typedef __bf16 bf16_t;
typedef __bf16 bf16x4 __attribute__((ext_vector_type(4)));
typedef __bf16 bf16x8 __attribute__((ext_vector_type(8)));
typedef float floatx4 __attribute__((ext_vector_type(4)));

#define N_NODES 32768
#define K_CENT  2048
#define D_DIM   512

// ---------------- prep: fp32 row -> bf16 row + sum of squares ----------------
// one wave per row (D=512 -> 8 floats/lane), 4 rows per 256-thread block
__global__ void prep_rows_kernel(const float* __restrict__ src,
                                 bf16_t* __restrict__ dst,
                                 float* __restrict__ sq) {
  const int w = threadIdx.x >> 6;
  const int l = threadIdx.x & 63;
  const int row = blockIdx.x * 4 + w;
  const float4* s = (const float4*)(src + (size_t)row * D_DIM);
  float4 f0 = s[l];
  float4 f1 = s[64 + l];
  bf16x4 b0 = { (bf16_t)f0.x, (bf16_t)f0.y, (bf16_t)f0.z, (bf16_t)f0.w };
  bf16x4 b1 = { (bf16_t)f1.x, (bf16_t)f1.y, (bf16_t)f1.z, (bf16_t)f1.w };
  bf16x4* d = (bf16x4*)(dst + (size_t)row * D_DIM);
  d[l] = b0;
  d[64 + l] = b1;
  float v = f0.x*f0.x + f0.y*f0.y + f0.z*f0.z + f0.w*f0.w
          + f1.x*f1.x + f1.y*f1.y + f1.z*f1.z + f1.w*f1.w;
  #pragma unroll
  for (int s2 = 32; s2; s2 >>= 1) v += __shfl_xor(v, s2);
  if (l == 0) sq[row] = v;
}

// ---------------- mask sum -> single scalar ----------------
__global__ void mask_sum_kernel(const float* __restrict__ m,
                                float* __restrict__ out, int n) {
  float v = 0.f;
  for (int i = blockIdx.x * blockDim.x + threadIdx.x; i < n;
       i += gridDim.x * blockDim.x)
    v += m[i];
  #pragma unroll
  for (int s = 32; s; s >>= 1) v += __shfl_xor(v, s);
  __shared__ float red[4];
  if ((threadIdx.x & 63) == 0) red[threadIdx.x >> 6] = v;
  __syncthreads();
  if (threadIdx.x == 0) atomicAdd(out, red[0] + red[1] + red[2] + red[3]);
}

// ---------------- async global -> LDS, 16B per lane ----------------
__device__ inline void gld_lds16(const void* g, void* l) {
  __builtin_amdgcn_global_load_lds(
      (__attribute__((address_space(1))) void*)const_cast<void*>(g),
      (__attribute__((address_space(3))) void*)l, 16, 0, 0);
}

// stage one 128x64 K-tile of A and B into the given LDS buffers.
// LDS dest is linear (gld_lds writes base + lane*16); the bank-conflict
// swizzle is applied on the GLOBAL source address instead (rule: both-sides
// via pre-swizzled source + swizzled read). gA/gB already carry the
// per-lane swizzled chunk offset.
__device__ __forceinline__ void stage_tile(const bf16_t* gA, const bf16_t* gB,
                                           bf16_t* sAb, bf16_t* sBb,
                                           int w, int kt) {
  char* lA = (char*)sAb + w * 1024;   // wave-uniform base
  char* lB = (char*)sBb + w * 1024;
  #pragma unroll
  for (int p = 0; p < 4; ++p) {
    gld_lds16(gA + (size_t)(p * 32) * D_DIM + kt, lA + p * 4096);
    gld_lds16(gB + (size_t)(p * 32) * D_DIM + kt, lB + p * 4096);
  }
}

// ---------------- GEMM + fused distance epilogue ----------------
// C = A (N x D) * B^T (K x D); per 128x128 tile:
//   dist = sqrt(max(x2[n] + c2[k] - 2*dot, EPS)) * mask[n]
//   out_node[n*K + k] = dist ; colsum[k] += dist (block-reduced, then atomic)
__global__ void __launch_bounds__(256)
gemm_dist_kernel(const bf16_t* __restrict__ A,
                 const bf16_t* __restrict__ B,
                 const float* __restrict__ x2,
                 const float* __restrict__ c2,
                 const float* __restrict__ mask,
                 float* __restrict__ out_node,
                 float* __restrict__ colsum) {
  // double-buffered row-major tiles [128][64] bf16 (128 B rows).
  // LDS layout is linear; LDS(row, chunk c) holds DATA chunk c ^ (row&7)
  // (16 B chunks), so ds_read spreads quarter-groups across all 8 chunk
  // positions -> 2-way (free) instead of 16-way bank conflicts.
  __shared__ __align__(16) bf16_t sA[2][128 * 64];
  __shared__ __align__(16) bf16_t sB[2][128 * 64];

  const int t = threadIdx.x;
  const int w = t >> 6;        // wave 0..3
  const int l = t & 63;

  // XCD-aware bijective swizzle: 4096 blocks, 8 XCDs -> 512 each.
  // XCD x owns bm in [x*32, (x+1)*32), all 16 bn -> A panel fetched into
  // ONE L2 instead of 8 (FETCH 140 MB -> ~50 MB).
  const int wg = (blockIdx.x & 7) * 512 + (blockIdx.x >> 3);
  const int bm = wg >> 4;      // 0..255  (node-row block)
  const int bn = wg & 15;      // 0..15   (centroid block)

  const int wm = (w >> 1) * 64;
  const int wn = (w & 1) * 64;
  const int lr = l & 15;           // A-row / B-col within 16x16 tile
  const int hi = l >> 4;           // k-group within 32 (8 elems each)

  floatx4 acc[4][4] = {};

  // staging geometry: pass p, thread t loads row p*32 + w*8 + (l>>3);
  // row&7 == l>>3 for every pass/wave, so the swizzled source chunk is
  // (l&7) ^ (l>>3) for all 4 passes. Wave still covers 8 full 128B row
  // slices -> perfectly coalesced.
  const int srow = w * 8 + (l >> 3);
  const int scol = ((l & 7) ^ (l >> 3)) * 8;   // pre-swizzled source chunk
  const bf16_t* gA = A + (size_t)(bm * 128 + srow) * D_DIM + scol;
  const bf16_t* gB = B + (size_t)(bn * 128 + srow) * D_DIM + scol;

  // prologue: stage first K-tile
  stage_tile(gA, gB, sA[0], sB[0], w, 0);
  __syncthreads();

  int cur = 0;
  for (int tk = 0; tk < 8; ++tk) {
    // issue next tile's loads BEFORE computing current tile: HBM/L2 latency
    // hides under the 32 MFMAs; __syncthreads (vmcnt(0) drain) at the end
    // guarantees the staged data is resident before it is read.
    if (tk < 7)
      stage_tile(gA, gB, sA[cur ^ 1], sB[cur ^ 1], w, (tk + 1) * 64);

    const char* cAb = (const char*)sA[cur];
    const char* cBb = (const char*)sB[cur];
    #pragma unroll
    for (int ks = 0; ks < 2; ++ks) {           // k-slice of 32
      bf16x8 af[4], bfr[4];
      #pragma unroll
      for (int i = 0; i < 4; ++i) {
        const int r = wm + i * 16 + lr;
        const int c = ((ks * 4 + hi) ^ (lr & 7)) * 16;  // swizzled read chunk
        af[i] = *(const bf16x8*)(cAb + r * 128 + c);
      }
      #pragma unroll
      for (int j = 0; j < 4; ++j) {
        const int r = wn + j * 16 + lr;
        const int c = ((ks * 4 + hi) ^ (lr & 7)) * 16;
        bfr[j] = *(const bf16x8*)(cBb + r * 128 + c);
      }
      #pragma unroll
      for (int i = 0; i < 4; ++i) {
        #pragma unroll
        for (int j = 0; j < 4; ++j)
          acc[i][j] = __builtin_amdgcn_mfma_f32_16x16x32_bf16(
              af[i], bfr[j], acc[i][j], 0, 0, 0);
      }
    }
    __syncthreads();
    cur ^= 1;
  }

  // ---- epilogue: C/D layout col = lane&15, row = (lane>>4)*4 + reg ----
  const int col0 = bn * 128 + wn;
  float c2v[4];
  #pragma unroll
  for (int j = 0; j < 4; ++j) c2v[j] = c2[col0 + j * 16 + lr];

  float colacc[4] = {0.f, 0.f, 0.f, 0.f};
  #pragma unroll
  for (int i = 0; i < 4; ++i) {
    const int rbase = bm * 128 + wm + i * 16 + hi * 4;
    #pragma unroll
    for (int r = 0; r < 4; ++r) {
      const int row = rbase + r;
      const float xv = x2[row];
      const float mk = mask[row];
      float* orow = out_node + (size_t)row * K_CENT + col0 + lr;
      #pragma unroll
      for (int j = 0; j < 4; ++j) {
        float d2 = xv + c2v[j] - 2.0f * acc[i][j][r];
        float dist = sqrtf(fmaxf(d2, 1e-12f));
        float dm = dist * mk;
        __builtin_nontemporal_store(dm, &orow[j * 16]);  // 256 MiB stream:
        colacc[j] += dm;                                 // don't evict A/B
      }
    }
  }

  // reduce column partials across the 4 row-groups of the wave
  #pragma unroll
  for (int j = 0; j < 4; ++j) {
    colacc[j] += __shfl_xor(colacc[j], 16);
    colacc[j] += __shfl_xor(colacc[j], 32);
  }
  // block-level reduce in LDS (reuse sA; safe: K-loop ended with a barrier)
  float* colbuf = (float*)sA;
  if (w < 2 && l < 16) {
    #pragma unroll
    for (int j = 0; j < 4; ++j) colbuf[wn + j * 16 + l] = colacc[j];
  }
  __syncthreads();
  if (w >= 2 && l < 16) {
    #pragma unroll
    for (int j = 0; j < 4; ++j) colbuf[wn + j * 16 + l] += colacc[j];
  }
  __syncthreads();
  if (t < 128) atomicAdd(&colsum[bn * 128 + t], colbuf[t]);
}

// ---------------- finalize: graph[k] = colsum[k] / masksum ----------------
__global__ void finalize_kernel(const float* __restrict__ colsum,
                                const float* __restrict__ msum,
                                float* __restrict__ out) {
  int k = blockIdx.x * 256 + threadIdx.x;
  out[k] = colsum[k] / msum[0];
}

extern "C" void kernel_launch(void* const* d_in, const int* in_sizes, int n_in,
                              void* d_out, int out_size, void* d_ws, size_t ws_size,
                              hipStream_t stream) {
  const float* node = (const float*)d_in[0];
  const float* mask = (const float*)d_in[1];
  const float* cent = (const float*)d_in[2];
  float* out_graph = (float*)d_out;            // [1, K] first in return order
  float* out_node  = out_graph + K_CENT;       // [1, N, K]

  char* ws = (char*)d_ws;
  size_t off = 0;
  bf16_t* Abf = (bf16_t*)(ws + off); off += (size_t)N_NODES * D_DIM * sizeof(bf16_t);
  bf16_t* Cbf = (bf16_t*)(ws + off); off += (size_t)K_CENT * D_DIM * sizeof(bf16_t);
  float* x2     = (float*)(ws + off); off += (size_t)N_NODES * sizeof(float);
  float* c2     = (float*)(ws + off); off += (size_t)K_CENT * sizeof(float);
  float* colsum = (float*)(ws + off); off += (size_t)K_CENT * sizeof(float);
  float* msum   = (float*)(ws + off); off += sizeof(float);

  // zero accumulators (colsum and msum are adjacent)
  hipMemsetAsync(colsum, 0, (K_CENT + 1) * sizeof(float), stream);

  prep_rows_kernel<<<N_NODES / 4, 256, 0, stream>>>(node, Abf, x2);
  prep_rows_kernel<<<K_CENT / 4, 256, 0, stream>>>(cent, Cbf, c2);
  mask_sum_kernel<<<64, 256, 0, stream>>>(mask, msum, N_NODES);
  gemm_dist_kernel<<<4096, 256, 0, stream>>>(
      Abf, Cbf, x2, c2, mask, out_node, colsum);
  finalize_kernel<<<K_CENT / 256, 256, 0, stream>>>(colsum, msum, out_graph);
}

// Round 4
// 413.139 us; speedup vs baseline: 1.0932x; 1.0932x over previous
//
#include <hip/hip_runtime.h>
#include <hip/hip_bf16.h>
#include <math.h>

typedef __bf16 bf16_t;
typedef __bf16 bf16x4 __attribute__((ext_vector_type(4)));
typedef __bf16 bf16x8 __attribute__((ext_vector_type(8)));
typedef float floatx4 __attribute__((ext_vector_type(4)));

#define N_NODES 32768
#define K_CENT  2048
#define D_DIM   512

// ---------------- prep: fp32 row -> bf16 row + sum of squares ----------------
__global__ void prep_rows_kernel(const float* __restrict__ src,
                                 bf16_t* __restrict__ dst,
                                 float* __restrict__ sq) {
  const int w = threadIdx.x >> 6;
  const int l = threadIdx.x & 63;
  const int row = blockIdx.x * 4 + w;
  const float4* s = (const float4*)(src + (size_t)row * D_DIM);
  float4 f0 = s[l];
  float4 f1 = s[64 + l];
  bf16x4 b0 = { (bf16_t)f0.x, (bf16_t)f0.y, (bf16_t)f0.z, (bf16_t)f0.w };
  bf16x4 b1 = { (bf16_t)f1.x, (bf16_t)f1.y, (bf16_t)f1.z, (bf16_t)f1.w };
  bf16x4* d = (bf16x4*)(dst + (size_t)row * D_DIM);
  d[l] = b0;
  d[64 + l] = b1;
  float v = f0.x*f0.x + f0.y*f0.y + f0.z*f0.z + f0.w*f0.w
          + f1.x*f1.x + f1.y*f1.y + f1.z*f1.z + f1.w*f1.w;
  #pragma unroll
  for (int s2 = 32; s2; s2 >>= 1) v += __shfl_xor(v, s2);
  if (l == 0) sq[row] = v;
}

// ---------------- mask sum -> single scalar ----------------
__global__ void mask_sum_kernel(const float* __restrict__ m,
                                float* __restrict__ out, int n) {
  float v = 0.f;
  for (int i = blockIdx.x * blockDim.x + threadIdx.x; i < n;
       i += gridDim.x * blockDim.x)
    v += m[i];
  #pragma unroll
  for (int s = 32; s; s >>= 1) v += __shfl_xor(v, s);
  __shared__ float red[4];
  if ((threadIdx.x & 63) == 0) red[threadIdx.x >> 6] = v;
  __syncthreads();
  if (threadIdx.x == 0) atomicAdd(out, red[0] + red[1] + red[2] + red[3]);
}

// ---------------- async global -> LDS, 16B per lane ----------------
__device__ inline void gld_lds16(const void* g, void* l) {
  __builtin_amdgcn_global_load_lds(
      (__attribute__((address_space(1))) void*)const_cast<void*>(g),
      (__attribute__((address_space(3))) void*)l, 16, 0, 0);
}

// counted-vmcnt gates (compiler memory fence via clobber: no LDS access may
// be moved across these -> protects ring-buffer slot reuse at compile time)
#define S_WAITV8 asm volatile("s_waitcnt vmcnt(8)" ::: "memory")
#define S_WAITV4 asm volatile("s_waitcnt vmcnt(4)" ::: "memory")
#define S_WAITV0 asm volatile("s_waitcnt vmcnt(0)" ::: "memory")

// ---------------- GEMM + fused distance epilogue ----------------
// 256x256 tile, BK=32, 8 waves (2M x 4N), 512 threads.
// LDS: ring of 4 K-tile buffers for A and B (4 x 16KB each = 128KB total).
// Pipeline: lead-3 prefetch, counted vmcnt(8) gate once per K-tile (never a
// full drain in steady state), raw s_barrier, setprio(1) around MFMA clusters.
__global__ void __launch_bounds__(512, 2)
gemm_dist_kernel(const bf16_t* __restrict__ A,
                 const bf16_t* __restrict__ B,
                 const float* __restrict__ x2,
                 const float* __restrict__ c2,
                 const float* __restrict__ mask,
                 float* __restrict__ out_node,
                 float* __restrict__ colsum) {
  // [256 rows][32 cols] bf16 per K-tile = 64B rows = 4 chunks of 16B.
  // Swizzle: LDS(row, c) holds DATA chunk c ^ ((row>>1)&3); staging applies
  // the inverse on the global source (gld_lds dest must stay linear), reads
  // apply it on the chunk index -> uniform granule load = conflict-free.
  __shared__ __align__(16) bf16_t sA[4][256 * 32];
  __shared__ __align__(16) bf16_t sB[4][256 * 32];

  const int t = threadIdx.x;
  const int w = t >> 6;          // wave 0..7
  const int l = t & 63;
  const int lr = l & 15;         // row-in-frag (A/B operand), col (C/D)
  const int hi = l >> 4;         // k-group (operand), row-group (C/D)

  // XCD-aware bijective swizzle: 1024 blocks = 8 XCDs x 128.
  // Each XCD: 16 consecutive bm x all 8 bn -> B (2MB) + A-panel (4MB) L2-fit.
  const int wg = (blockIdx.x & 7) * 128 + (blockIdx.x >> 3);
  const int bm = wg >> 3;        // 0..127
  const int bn = wg & 7;         // 0..7

  const int wm = (w >> 2) * 128; // wave M-offset (0 or 128)
  const int wn = (w & 3) * 64;   // wave N-offset (0,64,128,192)

  floatx4 acc[8][4] = {};

  // ---- staging geometry (per-thread): load q covers rows q*128 + (t>>2),
  // stored chunk t&3; pre-swizzled data chunk = (t&3) ^ ((t>>3)&3).
  const int srow = t >> 2;
  const int scolE = (((t & 3) ^ ((t >> 3) & 3)) << 3);  // element offset
  const bf16_t* gA = A + (size_t)(bm * 256 + srow) * D_DIM + scolE;
  const bf16_t* gB = B + (size_t)(bn * 256 + srow) * D_DIM + scolE;
  char* ldsAw = (char*)sA + w * 1024;   // wave-uniform; HW adds lane*16
  char* ldsBw = (char*)sB + w * 1024;

  auto stageA = [&](int kt) {
    const int sb = (kt & 3) * 16384;
    #pragma unroll
    for (int q = 0; q < 2; ++q)
      gld_lds16(gA + (size_t)(q * 128) * D_DIM + kt * 32,
                ldsAw + sb + q * 8192);
  };
  auto stageB = [&](int kt) {
    const int sb = (kt & 3) * 16384;
    #pragma unroll
    for (int q = 0; q < 2; ++q)
      gld_lds16(gB + (size_t)(q * 128) * D_DIM + kt * 32,
                ldsBw + sb + q * 8192);
  };

  // ---- fragment-read geometry: row = {wm|wn} + ph*64 + i*16 + lr,
  // byte = row*64 + ((hi ^ ((lr>>1)&3))*16  (swizzle-consistent, 2-way free)
  const int cOff = ((hi ^ ((lr >> 1) & 3)) << 4);
  const int aRow = wm + lr;
  const int bRow = wn + lr;

  // one K-tile: 2 phases (M-halves), 16 MFMA each, staged prefetch of kt+3
  auto tile = [&](int kt, bool doStage) {
    const char* aS = (const char*)sA + (kt & 3) * 16384;
    const char* bS = (const char*)sB + (kt & 3) * 16384;
    bf16x8 af[4], bfr[4];
    // -------- phase 0: M-rows wm..wm+63 --------
    if (doStage) stageA(kt + 3);
    #pragma unroll
    for (int j = 0; j < 4; ++j)
      bfr[j] = *(const bf16x8*)(bS + ((bRow + j * 16) << 6) + cOff);
    #pragma unroll
    for (int i = 0; i < 4; ++i)
      af[i] = *(const bf16x8*)(aS + ((aRow + i * 16) << 6) + cOff);
    __builtin_amdgcn_s_setprio(1);
    #pragma unroll
    for (int i = 0; i < 4; ++i)
      #pragma unroll
      for (int j = 0; j < 4; ++j)
        acc[i][j] = __builtin_amdgcn_mfma_f32_16x16x32_bf16(
            af[i], bfr[j], acc[i][j], 0, 0, 0);
    __builtin_amdgcn_s_setprio(0);
    __builtin_amdgcn_s_barrier();   // lockstep (no data hazard here)
    // -------- phase 1: M-rows wm+64..wm+127 --------
    if (doStage) stageB(kt + 3);
    #pragma unroll
    for (int i = 0; i < 4; ++i)
      af[i] = *(const bf16x8*)(aS + ((aRow + 64 + i * 16) << 6) + cOff);
    __builtin_amdgcn_s_setprio(1);
    #pragma unroll
    for (int i = 0; i < 4; ++i)
      #pragma unroll
      for (int j = 0; j < 4; ++j)
        acc[4 + i][j] = __builtin_amdgcn_mfma_f32_16x16x32_bf16(
            af[i], bfr[j], acc[4 + i][j], 0, 0, 0);
    __builtin_amdgcn_s_setprio(0);
  };

  // ---- prologue: stage K-tiles 0,1,2 (12 loads); wait until only the
  // youngest 8 (kt1,kt2) are in flight -> kt0 resident; barrier.
  stageA(0); stageB(0); stageA(1); stageB(1); stageA(2); stageB(2);
  S_WAITV8;
  __builtin_amdgcn_s_barrier();

  // ---- main loop: kt 0..12 stage kt+3; gate vmcnt(8) = {kt+2,kt+3} in
  // flight, everything older (incl. kt+1) complete. Tail gates shrink.
  #pragma unroll 1
  for (int kt = 0; kt < 13; ++kt) {
    tile(kt, true);
    S_WAITV8;
    __builtin_amdgcn_s_barrier();
  }
  tile(13, false); S_WAITV4; __builtin_amdgcn_s_barrier();
  tile(14, false); S_WAITV0; __builtin_amdgcn_s_barrier();
  tile(15, false);

  // ---- epilogue: C/D layout col = lane&15, row = hi*4 + reg ----
  const int col0 = bn * 256 + wn;
  float c2v[4];
  #pragma unroll
  for (int j = 0; j < 4; ++j) c2v[j] = c2[col0 + j * 16 + lr];

  float colacc[4] = {0.f, 0.f, 0.f, 0.f};
  #pragma unroll
  for (int ai = 0; ai < 8; ++ai) {
    const int rbase = bm * 256 + wm + ai * 16 + hi * 4;
    #pragma unroll
    for (int r = 0; r < 4; ++r) {
      const int row = rbase + r;
      const float xv = x2[row];
      const float mk = mask[row];
      float* orow = out_node + (size_t)row * K_CENT + col0 + lr;
      #pragma unroll
      for (int j = 0; j < 4; ++j) {
        float d2 = xv + c2v[j] - 2.0f * acc[ai][j][r];
        float dist = sqrtf(fmaxf(d2, 1e-12f));
        float dm = dist * mk;
        orow[j * 16] = dm;           // plain store: L2 write-combining
        colacc[j] += dm;
      }
    }
  }

  // reduce col partials across hi-groups (same col, different rows)
  #pragma unroll
  for (int j = 0; j < 4; ++j) {
    colacc[j] += __shfl_xor(colacc[j], 16);
    colacc[j] += __shfl_xor(colacc[j], 32);
  }
  // combine the two M-half waves per col range via LDS, then one atomic/col
  __syncthreads();                  // LDS reuse safe: K-loop fully consumed
  float* colbuf = (float*)sA;       // 256 floats
  if ((w >> 2) == 0 && l < 16) {
    #pragma unroll
    for (int j = 0; j < 4; ++j) colbuf[wn + j * 16 + l] = colacc[j];
  }
  __syncthreads();
  if ((w >> 2) == 1 && l < 16) {
    #pragma unroll
    for (int j = 0; j < 4; ++j) colbuf[wn + j * 16 + l] += colacc[j];
  }
  __syncthreads();
  if (t < 256) atomicAdd(&colsum[bn * 256 + t], colbuf[t]);
}

// ---------------- finalize: graph[k] = colsum[k] / masksum ----------------
__global__ void finalize_kernel(const float* __restrict__ colsum,
                                const float* __restrict__ msum,
                                float* __restrict__ out) {
  int k = blockIdx.x * 256 + threadIdx.x;
  out[k] = colsum[k] / msum[0];
}

extern "C" void kernel_launch(void* const* d_in, const int* in_sizes, int n_in,
                              void* d_out, int out_size, void* d_ws, size_t ws_size,
                              hipStream_t stream) {
  const float* node = (const float*)d_in[0];
  const float* mask = (const float*)d_in[1];
  const float* cent = (const float*)d_in[2];
  float* out_graph = (float*)d_out;            // [1, K] first in return order
  float* out_node  = out_graph + K_CENT;       // [1, N, K]

  char* ws = (char*)d_ws;
  size_t off = 0;
  bf16_t* Abf = (bf16_t*)(ws + off); off += (size_t)N_NODES * D_DIM * sizeof(bf16_t);
  bf16_t* Cbf = (bf16_t*)(ws + off); off += (size_t)K_CENT * D_DIM * sizeof(bf16_t);
  float* x2     = (float*)(ws + off); off += (size_t)N_NODES * sizeof(float);
  float* c2     = (float*)(ws + off); off += (size_t)K_CENT * sizeof(float);
  float* colsum = (float*)(ws + off); off += (size_t)K_CENT * sizeof(float);
  float* msum   = (float*)(ws + off); off += sizeof(float);

  hipMemsetAsync(colsum, 0, (K_CENT + 1) * sizeof(float), stream);

  prep_rows_kernel<<<N_NODES / 4, 256, 0, stream>>>(node, Abf, x2);
  prep_rows_kernel<<<K_CENT / 4, 256, 0, stream>>>(cent, Cbf, c2);
  mask_sum_kernel<<<64, 256, 0, stream>>>(mask, msum, N_NODES);
  gemm_dist_kernel<<<1024, 512, 0, stream>>>(
      Abf, Cbf, x2, c2, mask, out_node, colsum);
  finalize_kernel<<<K_CENT / 256, 256, 0, stream>>>(colsum, msum, out_graph);
}